// Round 4
// baseline (113.569 us; speedup 1.0000x reference)
//
#include <hip/hip_runtime.h>
#include <cstdint>
#include <climits>

#define EPSF 1e-7f
#define NCELL 1000          // 10x10x10 cells per batch, cell size 0.1 = radius
#define RPAD 0.10002f       // radius + fuzz for f32 binning boundary safety
#define MAXG 6              // 6*64 = 384 candidate slots, covers max window

__device__ __forceinline__ int cell_of(float x, float y, float z) {
    int cx = min(max((int)(x * 10.0f), 0), 9);
    int cy = min(max((int)(y * 10.0f), 0), 9);
    int cz = min(max((int)(z * 10.0f), 0), 9);
    return (cx * 10 + cy) * 10 + cz;
}

// ---------------------------------------------------------------------------
// K1: (a) per-face normal scattered into per-vertex accumulators (atomics,
//     spread over 108 blocks so the random coord gathers stay distributed);
//     (b) per-vertex grid-cell histogram. Unchanged from R3 (worked).
// ---------------------------------------------------------------------------
__global__ void k1_face_count(const float* __restrict__ hs,
                              const int* __restrict__ hf,
                              float* __restrict__ svec,
                              float* __restrict__ scnt,
                              int* __restrict__ counts,
                              int n_v, int n_f, int bs) {
    int t = blockIdx.x * blockDim.x + threadIdx.x;
    if (t < bs * n_f) {
        int b = t / n_f;
        int f = t - b * n_f;
        const int* fb = hf + (size_t)b * 3 * n_f;
        int i0 = fb[f];
        int i1 = fb[n_f + f];
        int i2 = fb[2 * n_f + f];
        const float* xs = hs + (size_t)b * 6 * n_v;
        const float* ys = xs + n_v;
        const float* zs = xs + 2 * n_v;
        float ax = xs[i0], ay = ys[i0], az = zs[i0];
        float bx = xs[i1], by = ys[i1], bz = zs[i1];
        float cx = xs[i2], cy = ys[i2], cz = zs[i2];
        float e1x = bx - ax, e1y = by - ay, e1z = bz - az;
        float e2x = cx - ax, e2y = cy - ay, e2z = cz - az;
        float fx = e1y * e2z - e1z * e2y;
        float fy = e1z * e2x - e1x * e2z;
        float fz = e1x * e2y - e1y * e2x;
        float nrm = sqrtf(fx * fx + fy * fy + fz * fz) + EPSF;
        fx /= nrm; fy /= nrm; fz /= nrm;
        float* sb = svec + (size_t)b * n_v * 3;
        float* cb = scnt + (size_t)b * n_v;
        int idx3[3] = {i0, i1, i2};
        #pragma unroll
        for (int k = 0; k < 3; ++k) {
            int i = idx3[k];
            atomicAdd(&sb[i * 3 + 0], fx);
            atomicAdd(&sb[i * 3 + 1], fy);
            atomicAdd(&sb[i * 3 + 2], fz);
            atomicAdd(&cb[i], 1.0f);
        }
    }
    if (t < bs * n_v) {
        int b = t / n_v;
        int v = t - b * n_v;
        const float* xs = hs + (size_t)b * 6 * n_v;
        float x = xs[v], y = xs[n_v + v], z = xs[2 * n_v + v];
        atomicAdd(&counts[b * NCELL + cell_of(x, y, z)], 1);
    }
}

// ---------------------------------------------------------------------------
// K2 (fused): blocks [0, nvb): vertex unit normals -> packed vert[] array
//   (float4 coords, float4 normal per vertex: epilogue = 2 dwordx4 loads).
// blocks nvb..nvb+1: per-batch grid build: wave 0 scans the 1000-cell
//   histogram (shuffle scan, writes cellstart global + cursor LDS), then all
//   256 threads scatter vertices into cell-sorted spk via LDS atomics.
// Both roles depend only on K1 -> safe in one kernel (no cross-block deps).
// ---------------------------------------------------------------------------
__global__ void k2_build(const float* __restrict__ hs,
                         const float* __restrict__ svec,
                         const float* __restrict__ scnt,
                         const int* __restrict__ counts,
                         int* __restrict__ cellstart,
                         float4* __restrict__ vert,
                         float4* __restrict__ spk,
                         int n_v, int bs, int nvb) {
    __shared__ int cursor_l[NCELL];
    if (blockIdx.x < (unsigned)nvb) {
        int t = blockIdx.x * blockDim.x + threadIdx.x;
        if (t >= bs * n_v) return;
        int b = t / n_v;
        int v = t - b * n_v;
        float cc = scnt[t] + EPSF;
        float vx = svec[t * 3 + 0] / cc;
        float vy = svec[t * 3 + 1] / cc;
        float vz = svec[t * 3 + 2] / cc;
        float nrm = sqrtf(vx * vx + vy * vy + vz * vz) + EPSF;
        const float* xs = hs + (size_t)b * 6 * n_v;
        float x = xs[v], y = xs[n_v + v], z = xs[2 * n_v + v];
        vert[2 * (size_t)t + 0] = make_float4(x, y, z, 0.0f);
        vert[2 * (size_t)t + 1] = make_float4(vx / nrm, vy / nrm, vz / nrm, 0.0f);
        return;
    }
    // grid-build block for one batch
    int batch = blockIdx.x - nvb;
    if (threadIdx.x < 64) {
        int lane = threadIdx.x;
        int local[16];
        int mysum = 0;
        #pragma unroll
        for (int k = 0; k < 16; ++k) {
            int c = lane * 16 + k;
            int v = (c < NCELL) ? counts[batch * NCELL + c] : 0;
            local[k] = v;
            mysum += v;
        }
        int s = mysum;
        #pragma unroll
        for (int off = 1; off < 64; off <<= 1) {
            int n = __shfl_up(s, off);
            if (lane >= off) s += n;
        }
        int excl = s - mysum;
        #pragma unroll
        for (int k = 0; k < 16; ++k) {
            int c = lane * 16 + k;
            if (c < NCELL) {
                cellstart[batch * (NCELL + 1) + c] = excl;
                cursor_l[c] = excl;
                excl += local[k];
            }
        }
        if (lane == 63) cellstart[batch * (NCELL + 1) + NCELL] = s;
    }
    __syncthreads();
    const float* xs = hs + (size_t)batch * 6 * n_v;
    for (int v = threadIdx.x; v < n_v; v += blockDim.x) {
        float x = xs[v], y = xs[n_v + v], z = xs[2 * n_v + v];
        int cell = cell_of(x, y, z);
        int pos = atomicAdd(&cursor_l[cell], 1);
        spk[(size_t)batch * n_v + pos] = make_float4(x, y, z, __int_as_float(v));
    }
}

// ---------------------------------------------------------------------------
// K3: one wave per query.
//  - 18 independent cellstart loads -> 9 z-run ranges, in-register prefix sum
//    (wave-uniform, no shuffles) -> T total candidates.
//  - candidate loads issued in ONE grouped batch (up to 6x64, clamped
//    addresses, exact predicate on processing) -> ~2 dependent rounds instead
//    of 9 serial per-row loops.
//  - per-lane sorted min-4, then 6-step bitonic partial merge across lanes
//    (4 parallel shfl_xor + 12 min/max per step) -> global 4 smallest ids
//    in every lane. Ids unique => exact. == ball query "first 4 in id order".
//  - epilogue: 2 dwordx4 loads per id from vert[]. Same arithmetic as R1-R3
//    (bit-exact so far). No fences (R2 lesson).
// ---------------------------------------------------------------------------
__global__ void k3_query(const float* __restrict__ pred,
                         const float4* __restrict__ vert,
                         const float4* __restrict__ spk,
                         const int* __restrict__ cellstart,
                         double* __restrict__ partial,
                         float* __restrict__ pcnt,
                         int n_v, int n_pred, int bs) {
    const int lane = threadIdx.x & 63;
    const int wave = threadIdx.x >> 6;
    const int wid = blockIdx.x * 4 + wave;
    const int nq = bs * n_pred;

    float per_pt = 0.0f;
    float is_pos = 0.0f;

    if (wid < nq) {
        const int b = wid / n_pred;
        const float4* vb = vert + 2 * (size_t)b * n_v;
        const float4* sp = spk + (size_t)b * n_v;
        const int* csb = cellstart + b * (NCELL + 1);
        const float px = pred[(size_t)wid * 3 + 0];
        const float py = pred[(size_t)wid * 3 + 1];
        const float pz = pred[(size_t)wid * 3 + 2];

        int xlo = max(0, (int)floorf((px - RPAD) * 10.0f));
        int xhi = min(9, (int)floorf((px + RPAD) * 10.0f));
        int ylo = max(0, (int)floorf((py - RPAD) * 10.0f));
        int yhi = min(9, (int)floorf((py + RPAD) * 10.0f));
        int zlo = max(0, (int)floorf((pz - RPAD) * 10.0f));
        int zhi = min(9, (int)floorf((pz + RPAD) * 10.0f));

        // 9 z-run ranges, all loads independent (one latency round)
        int rs[9], re[9];
        #pragma unroll
        for (int i = 0; i < 9; ++i) {
            int cx = xlo + i / 3;
            int cy = ylo + i % 3;
            bool valid = (cx <= xhi) && (cy <= yhi);
            int rowbase = (min(cx, 9) * 10 + min(cy, 9)) * 10;
            int lo = csb[rowbase + zlo];
            int hi = csb[rowbase + zhi + 1];
            rs[i] = valid ? lo : 0;
            re[i] = valid ? hi : 0;
        }
        // in-register prefix over 9 run lengths (wave-uniform values)
        int B[10];
        B[0] = 0;
        #pragma unroll
        for (int i = 0; i < 9; ++i) B[i + 1] = B[i] + (re[i] - rs[i]);
        const int T = B[9];
        int D[9];
        #pragma unroll
        for (int i = 0; i < 9; ++i) D[i] = rs[i] - B[i];

        int l0 = INT_MAX, l1 = INT_MAX, l2 = INT_MAX, l3 = INT_MAX;

        if (T > 0) {
            // grouped loads: all candidate loads issued before any use
            float4 cbuf[MAXG];
            #pragma unroll
            for (int g = 0; g < MAXG; ++g) {
                if (g * 64 < T) {
                    int pc = min(g * 64 + lane, T - 1);
                    int addr = pc + D[0];
                    #pragma unroll
                    for (int i = 1; i < 9; ++i)
                        addr = (pc >= B[i]) ? pc + D[i] : addr;
                    cbuf[g] = sp[addr];
                }
            }
            #pragma unroll
            for (int g = 0; g < MAXG; ++g) {
                if (g * 64 < T) {
                    int p = g * 64 + lane;
                    if (p < T) {
                        float4 c4 = cbuf[g];
                        float dx = px - c4.x;
                        float dy = py - c4.y;
                        float dz = pz - c4.z;
                        float d2 = dx * dx + dy * dy + dz * dz;
                        if (d2 < 0.01f) {     // 0.01f == f32(0.1*0.1)
                            int vid = __float_as_int(c4.w);
                            if (vid < l3) {
                                if (vid < l1) {
                                    if (vid < l0) { l3 = l2; l2 = l1; l1 = l0; l0 = vid; }
                                    else          { l3 = l2; l2 = l1; l1 = vid; }
                                } else {
                                    if (vid < l2) { l3 = l2; l2 = vid; }
                                    else          { l3 = vid; }
                                }
                            }
                        }
                    }
                }
            }
            // safety tail (never taken for this data; kept for rigor)
            for (int p = MAXG * 64 + lane; p < T; p += 64) {
                int addr = p + D[0];
                #pragma unroll
                for (int i = 1; i < 9; ++i)
                    addr = (p >= B[i]) ? p + D[i] : addr;
                float4 c4 = sp[addr];
                float dx = px - c4.x;
                float dy = py - c4.y;
                float dz = pz - c4.z;
                float d2 = dx * dx + dy * dy + dz * dz;
                if (d2 < 0.01f) {
                    int vid = __float_as_int(c4.w);
                    if (vid < l3) {
                        if (vid < l1) {
                            if (vid < l0) { l3 = l2; l2 = l1; l1 = l0; l0 = vid; }
                            else          { l3 = l2; l2 = l1; l1 = vid; }
                        } else {
                            if (vid < l2) { l3 = l2; l2 = vid; }
                            else          { l3 = vid; }
                        }
                    }
                }
            }
        }

        // bitonic partial merge across lanes: 6 steps, depth ~500 cyc
        // (vs 24 dependent shuffles before). Ids unique -> exact smallest-4.
        #pragma unroll
        for (int off = 1; off < 64; off <<= 1) {
            int r0 = __shfl_xor(l3, off);   // partner reversed
            int r1 = __shfl_xor(l2, off);
            int r2 = __shfl_xor(l1, off);
            int r3 = __shfl_xor(l0, off);
            int m0 = min(l0, r0);
            int m1 = min(l1, r1);
            int m2 = min(l2, r2);
            int m3 = min(l3, r3);
            // m is bitonic; sort with 4 compare-exchanges
            int t0 = min(m0, m2), t2 = max(m0, m2);
            int t1 = min(m1, m3), t3 = max(m1, m3);
            l0 = min(t0, t1); l1 = max(t0, t1);
            l2 = min(t2, t3); l3 = max(t2, t3);
        }

        int id0 = (l0 == INT_MAX) ? 0 : l0;      // no hits -> index 0 (ref argmax)
        int id1 = (l1 == INT_MAX) ? id0 : l1;    // unfilled -> first hit
        int id2 = (l2 == INT_MAX) ? id0 : l2;
        int id3 = (l3 == INT_MAX) ? id0 : l3;
        int ids[4] = {id0, id1, id2, id3};

        float vd[4];
        float cm = 0.0f;
        #pragma unroll
        for (int j = 0; j < 4; ++j) {
            int id = ids[j];
            float4 cj = vb[2 * id + 0];
            float4 nj = vb[2 * id + 1];
            float dx = px - cj.x;
            float dy = py - cj.y;
            float dz = pz - cj.z;
            float dot = dx * nj.x + dy * nj.y + dz * nj.z;
            float w = (dot >= -0.1f) ? 1.0f : 0.0f;
            float v = (dot - 0.001f) * w;
            bool msk = v < 0.0f;
            vd[j] = msk ? v : 0.0f;
            cm += msk ? 1.0f : 0.0f;
        }
        float s = ((vd[0] + vd[1]) + vd[2]) + vd[3];
        float a = s / (cm + EPSF);
        per_pt = a * a;
        is_pos = (per_pt > 0.0f) ? 1.0f : 0.0f;
    }

    __shared__ float ls[4];
    __shared__ float lc[4];
    if (lane == 0) { ls[wave] = per_pt; lc[wave] = is_pos; }
    __syncthreads();
    if (threadIdx.x == 0) {
        partial[blockIdx.x] = (double)ls[0] + (double)ls[1] + (double)ls[2] + (double)ls[3];
        pcnt[blockIdx.x] = ((lc[0] + lc[1]) + lc[2]) + lc[3];
    }
}

// ---------------------------------------------------------------------------
// K4: single-block reduction of the block partials -> final scalar loss.
// ---------------------------------------------------------------------------
__global__ void finalize_kernel(const double* __restrict__ partial,
                                const float* __restrict__ pcnt,
                                int n, float* __restrict__ out) {
    double s = 0.0, c = 0.0;
    for (int i = threadIdx.x; i < n; i += blockDim.x) {
        s += partial[i];
        c += (double)pcnt[i];
    }
    #pragma unroll
    for (int off = 32; off > 0; off >>= 1) {
        s += __shfl_down(s, off);
        c += __shfl_down(c, off);
    }
    __shared__ double ws_s[4];
    __shared__ double ws_c[4];
    int wave = threadIdx.x >> 6;
    int lane = threadIdx.x & 63;
    if (lane == 0) { ws_s[wave] = s; ws_c[wave] = c; }
    __syncthreads();
    if (threadIdx.x == 0) {
        double S = ws_s[0] + ws_s[1] + ws_s[2] + ws_s[3];
        double C = ws_c[0] + ws_c[1] + ws_c[2] + ws_c[3];
        out[0] = (float)(S / (C + 1e-7));
    }
}

extern "C" void kernel_launch(void* const* d_in, const int* in_sizes, int n_in,
                              void* d_out, int out_size, void* d_ws, size_t ws_size,
                              hipStream_t stream) {
    const float* pred    = (const float*)d_in[0];
    const float* h_state = (const float*)d_in[2];
    const int*   h_faces = (const int*)d_in[3];
    float* out = (float*)d_out;

    const int bs = 2;
    const int n_pred = in_sizes[0] / (bs * 3);   // 8192
    const int n_v    = in_sizes[2] / (bs * 6);   // 6890
    const int n_f    = in_sizes[3] / (bs * 3);   // 13776
    const int nq = bs * n_pred;                  // 16384
    const int nblk = (nq + 3) / 4;               // 4096 blocks, 4 queries each

    // ---- workspace layout (float-element offsets from d_ws) ----
    size_t o_svec    = 0;                                  // bs*n_v*3 (zeroed)
    size_t o_scnt    = o_svec + (size_t)bs * n_v * 3;      // bs*n_v   (zeroed)
    size_t o_counts  = o_scnt + (size_t)bs * n_v;          // bs*1000  (zeroed)
    size_t o_zeroend = (o_counts + (size_t)bs * NCELL + 3) & ~(size_t)3;
    size_t o_cs      = o_zeroend;                          // bs*1001 i
    size_t o_partial = (o_cs + (size_t)bs * (NCELL + 1) + 1) & ~(size_t)1; // nblk d
    size_t o_pcnt    = o_partial + 2 * (size_t)nblk;       // nblk f
    size_t o_spk     = (o_pcnt + (size_t)nblk + 3) & ~(size_t)3;   // bs*n_v f4
    size_t o_vert    = o_spk + (size_t)bs * n_v * 4;               // bs*n_v*2 f4

    float* base = (float*)d_ws;
    float*  svec      = base + o_svec;
    float*  scnt      = base + o_scnt;
    int*    counts    = (int*)(base + o_counts);
    int*    cellstart = (int*)(base + o_cs);
    double* partial   = (double*)(base + o_partial);
    float*  pcnt      = base + o_pcnt;
    float4* spk       = (float4*)(base + o_spk);
    float4* vert      = (float4*)(base + o_vert);

    hipMemsetAsync(d_ws, 0, o_zeroend * sizeof(float), stream);

    int t1 = bs * n_f;   // >= bs*n_v, covers both fused jobs
    k1_face_count<<<(t1 + 255) / 256, 256, 0, stream>>>(
        h_state, h_faces, svec, scnt, counts, n_v, n_f, bs);

    int nvb = (bs * n_v + 255) / 256;            // 54 normalize blocks
    k2_build<<<nvb + bs, 256, 0, stream>>>(
        h_state, svec, scnt, counts, cellstart, vert, spk, n_v, bs, nvb);

    k3_query<<<nblk, 256, 0, stream>>>(
        pred, vert, spk, cellstart, partial, pcnt, n_v, n_pred, bs);

    finalize_kernel<<<1, 256, 0, stream>>>(partial, pcnt, nblk, out);
}

// Round 5
// 105.726 us; speedup vs baseline: 1.0742x; 1.0742x over previous
//
#include <hip/hip_runtime.h>
#include <cstdint>
#include <climits>

#define EPSF 1e-7f
#define NCELL 1000          // 10x10x10 cells per batch, cell size 0.1 = radius
#define RPAD 0.10002f       // radius + fuzz for f32 binning boundary safety

__device__ __forceinline__ int cell_of(float x, float y, float z) {
    int cx = min(max((int)(x * 10.0f), 0), 9);
    int cy = min(max((int)(y * 10.0f), 0), 9);
    int cz = min(max((int)(z * 10.0f), 0), 9);
    return (cx * 10 + cy) * 10 + cz;
}

// ---------------------------------------------------------------------------
// K1: (a) per-face normal scattered into per-vertex accumulators (atomics);
//     (b) per-vertex grid-cell histogram. Unchanged since R3 (works).
// ---------------------------------------------------------------------------
__global__ void k1_face_count(const float* __restrict__ hs,
                              const int* __restrict__ hf,
                              float* __restrict__ svec,
                              float* __restrict__ scnt,
                              int* __restrict__ counts,
                              int n_v, int n_f, int bs) {
    int t = blockIdx.x * blockDim.x + threadIdx.x;
    if (t < bs * n_f) {
        int b = t / n_f;
        int f = t - b * n_f;
        const int* fb = hf + (size_t)b * 3 * n_f;
        int i0 = fb[f];
        int i1 = fb[n_f + f];
        int i2 = fb[2 * n_f + f];
        const float* xs = hs + (size_t)b * 6 * n_v;
        const float* ys = xs + n_v;
        const float* zs = xs + 2 * n_v;
        float ax = xs[i0], ay = ys[i0], az = zs[i0];
        float bx = xs[i1], by = ys[i1], bz = zs[i1];
        float cx = xs[i2], cy = ys[i2], cz = zs[i2];
        float e1x = bx - ax, e1y = by - ay, e1z = bz - az;
        float e2x = cx - ax, e2y = cy - ay, e2z = cz - az;
        float fx = e1y * e2z - e1z * e2y;
        float fy = e1z * e2x - e1x * e2z;
        float fz = e1x * e2y - e1y * e2x;
        float nrm = sqrtf(fx * fx + fy * fy + fz * fz) + EPSF;
        fx /= nrm; fy /= nrm; fz /= nrm;
        float* sb = svec + (size_t)b * n_v * 3;
        float* cb = scnt + (size_t)b * n_v;
        int idx3[3] = {i0, i1, i2};
        #pragma unroll
        for (int k = 0; k < 3; ++k) {
            int i = idx3[k];
            atomicAdd(&sb[i * 3 + 0], fx);
            atomicAdd(&sb[i * 3 + 1], fy);
            atomicAdd(&sb[i * 3 + 2], fz);
            atomicAdd(&cb[i], 1.0f);
        }
    }
    if (t < bs * n_v) {
        int b = t / n_v;
        int v = t - b * n_v;
        const float* xs = hs + (size_t)b * 6 * n_v;
        float x = xs[v], y = xs[n_v + v], z = xs[2 * n_v + v];
        atomicAdd(&counts[b * NCELL + cell_of(x, y, z)], 1);
    }
}

// ---------------------------------------------------------------------------
// K2 (fused): normalize blocks + per-batch scan/scatter blocks (R4, works).
// ---------------------------------------------------------------------------
__global__ void k2_build(const float* __restrict__ hs,
                         const float* __restrict__ svec,
                         const float* __restrict__ scnt,
                         const int* __restrict__ counts,
                         int* __restrict__ cellstart,
                         float4* __restrict__ vert,
                         float4* __restrict__ spk,
                         int n_v, int bs, int nvb) {
    __shared__ int cursor_l[NCELL];
    if (blockIdx.x < (unsigned)nvb) {
        int t = blockIdx.x * blockDim.x + threadIdx.x;
        if (t >= bs * n_v) return;
        int b = t / n_v;
        int v = t - b * n_v;
        float cc = scnt[t] + EPSF;
        float vx = svec[t * 3 + 0] / cc;
        float vy = svec[t * 3 + 1] / cc;
        float vz = svec[t * 3 + 2] / cc;
        float nrm = sqrtf(vx * vx + vy * vy + vz * vz) + EPSF;
        const float* xs = hs + (size_t)b * 6 * n_v;
        float x = xs[v], y = xs[n_v + v], z = xs[2 * n_v + v];
        vert[2 * (size_t)t + 0] = make_float4(x, y, z, 0.0f);
        vert[2 * (size_t)t + 1] = make_float4(vx / nrm, vy / nrm, vz / nrm, 0.0f);
        return;
    }
    int batch = blockIdx.x - nvb;
    if (threadIdx.x < 64) {
        int lane = threadIdx.x;
        int local[16];
        int mysum = 0;
        #pragma unroll
        for (int k = 0; k < 16; ++k) {
            int c = lane * 16 + k;
            int v = (c < NCELL) ? counts[batch * NCELL + c] : 0;
            local[k] = v;
            mysum += v;
        }
        int s = mysum;
        #pragma unroll
        for (int off = 1; off < 64; off <<= 1) {
            int n = __shfl_up(s, off);
            if (lane >= off) s += n;
        }
        int excl = s - mysum;
        #pragma unroll
        for (int k = 0; k < 16; ++k) {
            int c = lane * 16 + k;
            if (c < NCELL) {
                cellstart[batch * (NCELL + 1) + c] = excl;
                cursor_l[c] = excl;
                excl += local[k];
            }
        }
        if (lane == 63) cellstart[batch * (NCELL + 1) + NCELL] = s;
    }
    __syncthreads();
    const float* xs = hs + (size_t)batch * 6 * n_v;
    for (int v = threadIdx.x; v < n_v; v += blockDim.x) {
        float x = xs[v], y = xs[n_v + v], z = xs[2 * n_v + v];
        int cell = cell_of(x, y, z);
        int pos = atomicAdd(&cursor_l[cell], 1);
        spk[(size_t)batch * n_v + pos] = make_float4(x, y, z, __int_as_float(v));
    }
}

// ---------------------------------------------------------------------------
// K3: QUARTER-WAVE queries — 16 lanes per query, 4 queries per wave.
// All wave-uniform per-query overhead (window calc, cellstart loads, merge,
// epilogue, reduction) is shared 4-ways per instruction:
//  - lanes 0..8 of each quarter load the 9 z-run (start,end) pairs in TWO
//    load instructions per wave (vs 18 per query before);
//  - candidate scan: per run, quarter's 16 lanes stride the run (same total
//    candidate-lane slots as before);
//  - per-lane sorted min-4, then 4-step quarter-local bitonic merge
//    (shfl_xor off=1,2,4,8 stays inside the 16-lane quarter);
//  - epilogue computed redundantly by all 16 lanes of the quarter
//    (quarter-uniform ids -> broadcast loads), bit-identical math to R1-R4.
// 1024 blocks x 16 queries; partial/pcnt per block, fp64 finalize.
// ---------------------------------------------------------------------------
__global__ void k3_query(const float* __restrict__ pred,
                         const float4* __restrict__ vert,
                         const float4* __restrict__ spk,
                         const int* __restrict__ cellstart,
                         double* __restrict__ partial,
                         float* __restrict__ pcnt,
                         int n_v, int n_pred, int bs) {
    const int lane = threadIdx.x & 63;
    const int wave = threadIdx.x >> 6;
    const int sub = lane & 15;          // lane within quarter
    const int qid = blockIdx.x * 16 + wave * 4 + (lane >> 4);
    const int nq = bs * n_pred;

    float per_pt = 0.0f;
    float is_pos = 0.0f;

    if (qid < nq) {
        const int b = qid / n_pred;
        const float4* vb = vert + 2 * (size_t)b * n_v;
        const float4* sp = spk + (size_t)b * n_v;
        const int* csb = cellstart + b * (NCELL + 1);
        const float px = pred[(size_t)qid * 3 + 0];
        const float py = pred[(size_t)qid * 3 + 1];
        const float pz = pred[(size_t)qid * 3 + 2];

        int xlo = max(0, (int)floorf((px - RPAD) * 10.0f));
        int xhi = min(9, (int)floorf((px + RPAD) * 10.0f));
        int ylo = max(0, (int)floorf((py - RPAD) * 10.0f));
        int yhi = min(9, (int)floorf((py + RPAD) * 10.0f));
        int zlo = max(0, (int)floorf((pz - RPAD) * 10.0f));
        int zhi = min(9, (int)floorf((pz + RPAD) * 10.0f));

        // lanes 0..8 of the quarter each own one (cx,cy) row: two loads give
        // all 9 z-run ranges for the quarter's query.
        int ip = min(sub, 8);
        int cx = xlo + ip / 3;
        int cy = ylo + ip % 3;
        bool valid = (cx <= xhi) && (cy <= yhi) && (sub < 9);
        int rowbase = (min(cx, 9) * 10 + min(cy, 9)) * 10;
        int rsv = csb[rowbase + zlo];
        int rev = csb[rowbase + zhi + 1];
        if (!valid) rev = rsv;          // empty run

        int l0 = INT_MAX, l1 = INT_MAX, l2 = INT_MAX, l3 = INT_MAX;
        #pragma unroll
        for (int i = 0; i < 9; ++i) {
            int rs = __shfl(rsv, i, 16);    // quarter-local broadcast
            int re = __shfl(rev, i, 16);
            for (int p = rs + sub; p < re; p += 16) {
                float4 c4 = sp[p];
                float dx = px - c4.x;
                float dy = py - c4.y;
                float dz = pz - c4.z;
                float d2 = dx * dx + dy * dy + dz * dz;
                if (d2 < 0.01f) {           // 0.01f == f32(0.1*0.1)
                    int vid = __float_as_int(c4.w);
                    if (vid < l3) {
                        if (vid < l1) {
                            if (vid < l0) { l3 = l2; l2 = l1; l1 = l0; l0 = vid; }
                            else          { l3 = l2; l2 = l1; l1 = vid; }
                        } else {
                            if (vid < l2) { l3 = l2; l2 = vid; }
                            else          { l3 = vid; }
                        }
                    }
                }
            }
        }

        // quarter-local bitonic partial merge: off=1,2,4,8 stays in-quarter.
        // Same step logic as R4 (bench-verified exact), 4 steps for 16 lanes.
        #pragma unroll
        for (int off = 1; off < 16; off <<= 1) {
            int r0 = __shfl_xor(l3, off);
            int r1 = __shfl_xor(l2, off);
            int r2 = __shfl_xor(l1, off);
            int r3 = __shfl_xor(l0, off);
            int m0 = min(l0, r0);
            int m1 = min(l1, r1);
            int m2 = min(l2, r2);
            int m3 = min(l3, r3);
            int t0 = min(m0, m2), t2 = max(m0, m2);
            int t1 = min(m1, m3), t3 = max(m1, m3);
            l0 = min(t0, t1); l1 = max(t0, t1);
            l2 = min(t2, t3); l3 = max(t2, t3);
        }

        int id0 = (l0 == INT_MAX) ? 0 : l0;      // no hits -> index 0
        int id1 = (l1 == INT_MAX) ? id0 : l1;    // unfilled -> first hit
        int id2 = (l2 == INT_MAX) ? id0 : l2;
        int id3 = (l3 == INT_MAX) ? id0 : l3;
        int ids[4] = {id0, id1, id2, id3};

        float vd[4];
        float cm = 0.0f;
        #pragma unroll
        for (int j = 0; j < 4; ++j) {
            int id = ids[j];
            float4 cj = vb[2 * id + 0];
            float4 nj = vb[2 * id + 1];
            float dx = px - cj.x;
            float dy = py - cj.y;
            float dz = pz - cj.z;
            float dot = dx * nj.x + dy * nj.y + dz * nj.z;
            float w = (dot >= -0.1f) ? 1.0f : 0.0f;
            float v = (dot - 0.001f) * w;
            bool msk = v < 0.0f;
            vd[j] = msk ? v : 0.0f;
            cm += msk ? 1.0f : 0.0f;
        }
        float s = ((vd[0] + vd[1]) + vd[2]) + vd[3];
        float a = s / (cm + EPSF);
        per_pt = a * a;
        is_pos = (per_pt > 0.0f) ? 1.0f : 0.0f;
    }

    __shared__ float ls[16];
    __shared__ float lc[16];
    if (sub == 0) {
        int slot = wave * 4 + (lane >> 4);
        ls[slot] = per_pt;
        lc[slot] = is_pos;
    }
    __syncthreads();
    if (threadIdx.x == 0) {
        double ssum = 0.0;
        float csum = 0.0f;
        #pragma unroll
        for (int k = 0; k < 16; ++k) {
            ssum += (double)ls[k];
            csum += lc[k];
        }
        partial[blockIdx.x] = ssum;
        pcnt[blockIdx.x] = csum;
    }
}

// ---------------------------------------------------------------------------
// K4: single-block reduction of the block partials -> final scalar loss.
// ---------------------------------------------------------------------------
__global__ void finalize_kernel(const double* __restrict__ partial,
                                const float* __restrict__ pcnt,
                                int n, float* __restrict__ out) {
    double s = 0.0, c = 0.0;
    for (int i = threadIdx.x; i < n; i += blockDim.x) {
        s += partial[i];
        c += (double)pcnt[i];
    }
    #pragma unroll
    for (int off = 32; off > 0; off >>= 1) {
        s += __shfl_down(s, off);
        c += __shfl_down(c, off);
    }
    __shared__ double ws_s[4];
    __shared__ double ws_c[4];
    int wave = threadIdx.x >> 6;
    int lane = threadIdx.x & 63;
    if (lane == 0) { ws_s[wave] = s; ws_c[wave] = c; }
    __syncthreads();
    if (threadIdx.x == 0) {
        double S = ws_s[0] + ws_s[1] + ws_s[2] + ws_s[3];
        double C = ws_c[0] + ws_c[1] + ws_c[2] + ws_c[3];
        out[0] = (float)(S / (C + 1e-7));
    }
}

extern "C" void kernel_launch(void* const* d_in, const int* in_sizes, int n_in,
                              void* d_out, int out_size, void* d_ws, size_t ws_size,
                              hipStream_t stream) {
    const float* pred    = (const float*)d_in[0];
    const float* h_state = (const float*)d_in[2];
    const int*   h_faces = (const int*)d_in[3];
    float* out = (float*)d_out;

    const int bs = 2;
    const int n_pred = in_sizes[0] / (bs * 3);   // 8192
    const int n_v    = in_sizes[2] / (bs * 6);   // 6890
    const int n_f    = in_sizes[3] / (bs * 3);   // 13776
    const int nq = bs * n_pred;                  // 16384
    const int nblk = (nq + 15) / 16;             // 1024 blocks, 16 queries each

    // ---- workspace layout (float-element offsets from d_ws) ----
    size_t o_svec    = 0;                                  // bs*n_v*3 (zeroed)
    size_t o_scnt    = o_svec + (size_t)bs * n_v * 3;      // bs*n_v   (zeroed)
    size_t o_counts  = o_scnt + (size_t)bs * n_v;          // bs*1000  (zeroed)
    size_t o_zeroend = (o_counts + (size_t)bs * NCELL + 3) & ~(size_t)3;
    size_t o_cs      = o_zeroend;                          // bs*1001 i
    size_t o_partial = (o_cs + (size_t)bs * (NCELL + 1) + 1) & ~(size_t)1; // nblk d
    size_t o_pcnt    = o_partial + 2 * (size_t)nblk;       // nblk f
    size_t o_spk     = (o_pcnt + (size_t)nblk + 3) & ~(size_t)3;   // bs*n_v f4
    size_t o_vert    = o_spk + (size_t)bs * n_v * 4;               // bs*n_v*2 f4

    float* base = (float*)d_ws;
    float*  svec      = base + o_svec;
    float*  scnt      = base + o_scnt;
    int*    counts    = (int*)(base + o_counts);
    int*    cellstart = (int*)(base + o_cs);
    double* partial   = (double*)(base + o_partial);
    float*  pcnt      = base + o_pcnt;
    float4* spk       = (float4*)(base + o_spk);
    float4* vert      = (float4*)(base + o_vert);

    hipMemsetAsync(d_ws, 0, o_zeroend * sizeof(float), stream);

    int t1 = bs * n_f;   // >= bs*n_v, covers both fused jobs
    k1_face_count<<<(t1 + 255) / 256, 256, 0, stream>>>(
        h_state, h_faces, svec, scnt, counts, n_v, n_f, bs);

    int nvb = (bs * n_v + 255) / 256;            // 54 normalize blocks
    k2_build<<<nvb + bs, 256, 0, stream>>>(
        h_state, svec, scnt, counts, cellstart, vert, spk, n_v, bs, nvb);

    k3_query<<<nblk, 256, 0, stream>>>(
        pred, vert, spk, cellstart, partial, pcnt, n_v, n_pred, bs);

    finalize_kernel<<<1, 256, 0, stream>>>(partial, pcnt, nblk, out);
}